// Round 1
// baseline (948.202 us; speedup 1.0000x reference)
//
#include <hip/hip_runtime.h>

typedef __attribute__((ext_vector_type(8))) short short8;
typedef __attribute__((ext_vector_type(16))) float f32x16;

#define NT 512

static __device__ __forceinline__ short f2bf(float f) {
    unsigned u = __float_as_uint(f);
    unsigned r = (u + 0x7FFFu + ((u >> 16) & 1u)) >> 16;
    return (short)r;
}
static __device__ __forceinline__ float bf2f(short s) {
    return __uint_as_float(((unsigned)(unsigned short)s) << 16);
}

// One workgroup per batch. LDS holds the bf16 image of h (rows = t+4, t in [-4,140)),
// swizzled: short_idx = (row*128 + c) ^ ((row&7)<<3)  (== byte ^ ((row&7)<<4)).
// fp32 master of h lives in each wave's registers (C-fragment layout).
__global__ __launch_bounds__(512, 2)
void vgt_kernel(const int* __restrict__ x,
                const float* __restrict__ emb_w,
                const float* __restrict__ red_w,
                const float* __restrict__ red_b,
                const float* __restrict__ conv_w,
                const float* __restrict__ conv_b,
                const float* __restrict__ out_w,
                const float* __restrict__ out_b,
                float* __restrict__ out)
{
    __shared__ short hb[144 * 128];   // bf16 h, swizzled rows; 36864 B
    __shared__ float m1[128][10];
    __shared__ float m2[128][10];
    __shared__ float owS[10][128];
    __shared__ float cbS[128];
    __shared__ float rbS[128];
    __shared__ float obS[16];
    __shared__ int   xbS[256];

    const int b    = blockIdx.x;
    const int tid  = threadIdx.x;
    const int lane = tid & 63;
    const int wv   = tid >> 6;     // 0..7
    const int wm   = wv & 3;       // M tile (output channels obase..obase+31)
    const int wh   = wv >> 2;      // t half
    const int obase = wm * 32;
    const int tbase = wh * 64;
    const int l31  = lane & 31;
    const int lhi  = lane >> 5;

    // ---------------- prologue ----------------
    for (int i = tid; i < 144 * 128 / 2; i += NT) ((int*)hb)[i] = 0;
    if (tid < 256) xbS[tid] = x[b * 256 + tid];
    if (tid < 128) { cbS[tid] = conv_b[tid]; rbS[tid] = red_b[tid]; }
    if (tid < 16)  obS[tid] = (tid < 10) ? out_b[tid] : 0.f;
    for (int i = tid; i < 1280; i += NT) ((float*)owS)[i] = out_w[i];
    // collapse embedding+reducer into two 128x10 tables
    for (int e = tid; e < 128 * 20; e += NT) {
        int o = e / 20, col = e % 20;
        int v = col % 10;
        const float* rw = red_w + o * 256 + ((col < 10) ? 0 : 128);
        const float* ew = emb_w + v * 128;
        float s = 0.f;
        for (int c = 0; c < 128; ++c) s += rw[c] * ew[c];
        if (col < 10) m1[o][v] = s; else m2[o][v] = s;
    }

    // A fragments (conv weights), resident in VGPRs: s = kk*8 + cb
    // A_kk[o][c]: lane l, elem j -> A[obase + (l&31)][cb*16 + (l>>5)*8 + j]
    short8 aw[24];
#pragma unroll
    for (int s = 0; s < 24; ++s) {
        int kk = s >> 3, cb = s & 7;
        int o = obase + l31;
        int c0 = cb * 16 + lhi * 8;
        short8 v;
#pragma unroll
        for (int j = 0; j < 8; ++j)
            v[j] = f2bf(conv_w[(o * 128 + c0 + j) * 3 + kk]);
        aw[s] = v;
    }

    // tail-column (t=128) weights: thread -> o = tid>>2, c-range [q*32, q*32+32)
    const int o_t = tid >> 2, q = tid & 3;
    unsigned twA[16], twB[16];
#pragma unroll
    for (int i = 0; i < 16; ++i) {
        int c = q * 32 + 2 * i;
        twA[i] = ((unsigned)(unsigned short)f2bf(conv_w[(o_t * 128 + c) * 3 + 0])) |
                 (((unsigned)(unsigned short)f2bf(conv_w[(o_t * 128 + c + 1) * 3 + 0])) << 16);
        twB[i] = ((unsigned)(unsigned short)f2bf(conv_w[(o_t * 128 + c) * 3 + 1])) |
                 (((unsigned)(unsigned short)f2bf(conv_w[(o_t * 128 + c + 1) * 3 + 1])) << 16);
    }
    float h128reg = 0.f;

    __syncthreads();

    // initial h (fp32 master in registers, C-fragment layout)
    float hr[2][16];
#pragma unroll
    for (int nn = 0; nn < 2; ++nn) {
        int t = tbase + nn * 32 + l31;           // all < 128
        int xv1 = xbS[t], xv2 = xbS[t + 128];
#pragma unroll
        for (int r = 0; r < 16; ++r) {
            int o = obase + (r & 3) + 8 * (r >> 2) + 4 * lhi;
            float s = m1[o][xv1] + m2[o][xv2] + rbS[o];
            hr[nn][r] = s > 0.f ? s : 0.f;
        }
    }
    // write initial bf16 image
#pragma unroll
    for (int nn = 0; nn < 2; ++nn) {
        int row = tbase + nn * 32 + l31 + 4;
#pragma unroll
        for (int g = 0; g < 4; ++g) {
            int o = obase + 8 * g + 4 * lhi;
            unsigned lo = ((unsigned)(unsigned short)f2bf(hr[nn][4*g+0])) |
                          (((unsigned)(unsigned short)f2bf(hr[nn][4*g+1])) << 16);
            unsigned hi = ((unsigned)(unsigned short)f2bf(hr[nn][4*g+2])) |
                          (((unsigned)(unsigned short)f2bf(hr[nn][4*g+3])) << 16);
            int idx = (row * 128 + o) ^ ((row & 7) << 3);
            *(unsigned long long*)&hb[idx] = ((unsigned long long)hi << 32) | lo;
        }
    }
    __syncthreads();

    // ---------------- 131 residual conv steps ----------------
    for (int it = 0; it < 131; ++it) {
        const int dd = (it < 4) ? 1 : ((it < 8) ? 2 : 4);

        f32x16 acc0 = {};
        f32x16 acc1 = {};
        {
            const int base0 = tbase + l31 + 4;
#pragma unroll
            for (int s = 0; s < 24; ++s) {
                int kk = s >> 3, cb = s & 7;
                int r0 = base0 + (kk - 1) * dd;
                int r1 = r0 + 32;
                int c0 = cb * 16 + lhi * 8;
                int i0 = (r0 * 128 + c0) ^ ((r0 & 7) << 3);
                int i1 = (r1 * 128 + c0) ^ ((r1 & 7) << 3);
                short8 b0 = *(const short8*)&hb[i0];
                short8 b1 = *(const short8*)&hb[i1];
                acc0 = __builtin_amdgcn_mfma_f32_32x32x16_bf16(aw[s], b0, acc0, 0, 0, 0);
                acc1 = __builtin_amdgcn_mfma_f32_32x32x16_bf16(aw[s], b1, acc1, 0, 0, 0);
            }
        }

        // tail column t=128: taps k=0 (t=128-dd) and k=1 (t=128); k=2 reads pad zeros
        float tsum = 0.f;
        {
            const int rowA = 132 - dd, rowB = 132;
#pragma unroll
            for (int i = 0; i < 16; ++i) {
                int c = q * 32 + 2 * i;
                int iA = (rowA * 128 + c) ^ ((rowA & 7) << 3);
                int iB = (rowB * 128 + c) ^ ((rowB & 7) << 3);
                unsigned ha = *(const unsigned*)&hb[iA];
                unsigned hc = *(const unsigned*)&hb[iB];
                float a_lo = __uint_as_float(ha << 16);
                float a_hi = __uint_as_float(ha & 0xffff0000u);
                float b_lo = __uint_as_float(hc << 16);
                float b_hi = __uint_as_float(hc & 0xffff0000u);
                tsum += a_lo * __uint_as_float(twA[i] << 16)
                      + a_hi * __uint_as_float(twA[i] & 0xffff0000u)
                      + b_lo * __uint_as_float(twB[i] << 16)
                      + b_hi * __uint_as_float(twB[i] & 0xffff0000u);
            }
        }
        tsum += __shfl_xor(tsum, 1);
        tsum += __shfl_xor(tsum, 2);
        float h128new = 0.f;
        if (q == 0) {
            float v = tsum + cbS[o_t];
            h128new = (v > 0.f ? v : 0.f) + h128reg;
        }

        __syncthreads();   // all reads of current hb done

        // write phase: h = relu(conv + bias) + h ; refresh bf16 image
#pragma unroll
        for (int nn = 0; nn < 2; ++nn) {
            const f32x16 ac = (nn == 0) ? acc0 : acc1;
            int row = tbase + nn * 32 + l31 + 4;
#pragma unroll
            for (int g = 0; g < 4; ++g) {
                int o = obase + 8 * g + 4 * lhi;
                float v0 = ac[4*g+0] + cbS[o+0]; v0 = (v0 > 0.f) ? v0 : 0.f;
                float v1 = ac[4*g+1] + cbS[o+1]; v1 = (v1 > 0.f) ? v1 : 0.f;
                float v2 = ac[4*g+2] + cbS[o+2]; v2 = (v2 > 0.f) ? v2 : 0.f;
                float v3 = ac[4*g+3] + cbS[o+3]; v3 = (v3 > 0.f) ? v3 : 0.f;
                float h0n = hr[nn][4*g+0] + v0;
                float h1n = hr[nn][4*g+1] + v1;
                float h2n = hr[nn][4*g+2] + v2;
                float h3n = hr[nn][4*g+3] + v3;
                hr[nn][4*g+0] = h0n; hr[nn][4*g+1] = h1n;
                hr[nn][4*g+2] = h2n; hr[nn][4*g+3] = h3n;
                unsigned lo = ((unsigned)(unsigned short)f2bf(h0n)) |
                              (((unsigned)(unsigned short)f2bf(h1n)) << 16);
                unsigned hi = ((unsigned)(unsigned short)f2bf(h2n)) |
                              (((unsigned)(unsigned short)f2bf(h3n)) << 16);
                int idx = (row * 128 + o) ^ ((row & 7) << 3);
                *(unsigned long long*)&hb[idx] = ((unsigned long long)hi << 32) | lo;
            }
        }
        if (q == 0) {
            h128reg = h128new;
            int idx = (132 * 128 + o_t) ^ ((132 & 7) << 3);
            hb[idx] = f2bf(h128reg);
        }
        __syncthreads();
    }

    // ---------------- output head ----------------
    for (int e = tid; e < 129 * 10; e += NT) {
        int t = e / 10, v = e % 10;
        int row = t + 4;
        float s = obS[v];
        for (int c = 0; c < 128; ++c) {
            int idx = (row * 128 + c) ^ ((row & 7) << 3);
            s += owS[v][c] * bf2f(hb[idx]);
        }
        out[(b * 129 + t) * 10 + v] = s;
    }
}

extern "C" void kernel_launch(void* const* d_in, const int* in_sizes, int n_in,
                              void* d_out, int out_size, void* d_ws, size_t ws_size,
                              hipStream_t stream) {
    const int*   x      = (const int*)d_in[0];
    const float* emb_w  = (const float*)d_in[1];
    const float* red_w  = (const float*)d_in[2];
    const float* red_b  = (const float*)d_in[3];
    const float* conv_w = (const float*)d_in[4];
    const float* conv_b = (const float*)d_in[5];
    const float* out_w  = (const float*)d_in[6];
    const float* out_b  = (const float*)d_in[7];
    (void)in_sizes; (void)n_in; (void)d_ws; (void)ws_size; (void)out_size;
    vgt_kernel<<<32, 512, 0, stream>>>(x, emb_w, red_w, red_b, conv_w, conv_b,
                                       out_w, out_b, (float*)d_out);
}